// Round 1
// baseline (1722.316 us; speedup 1.0000x reference)
//
#include <hip/hip_runtime.h>

typedef unsigned short u16;
typedef unsigned int   u32;
typedef __bf16 bf16x8 __attribute__((ext_vector_type(8)));
typedef float  f32x4  __attribute__((ext_vector_type(4)));

#define DEV __device__ __forceinline__

DEV u16 f2bf(float f) {
    u32 u = __builtin_bit_cast(u32, f);
    u32 r = u + 0x7FFFu + ((u >> 16) & 1u);
    return (u16)(r >> 16);
}

DEV void gload16(const void* g, void* l) {
    __builtin_amdgcn_global_load_lds((const __attribute__((address_space(1))) void*)g,
                                     (__attribute__((address_space(3))) void*)l, 16, 0, 0);
}

// ---------------- convert f32 -> bf16 (vectorized, grid-stride) ----------------
__global__ void cvt_k(const float* __restrict__ src, u16* __restrict__ dst, int n4) {
    int i = blockIdx.x * blockDim.x + threadIdx.x;
    int stride = gridDim.x * blockDim.x;
    for (; i < n4; i += stride) {
        float4 v = ((const float4*)src)[i];
        ushort4 u;
        u.x = f2bf(v.x); u.y = f2bf(v.y); u.z = f2bf(v.z); u.w = f2bf(v.w);
        ((ushort4*)dst)[i] = u;
    }
}

// ---------------- embedding: h[b,s,:] = tok_emb[x[b,s],:] + pos_emb[s,:] ----------------
__global__ void embed_k(const int* __restrict__ x, const float* __restrict__ te,
                        const float* __restrict__ pe, float* __restrict__ h) {
    int row = blockIdx.x;          // b*1024 + s
    int t = threadIdx.x;           // 256 threads * float4
    int tok = x[row];
    int s = row & 1023;
    float4 a = ((const float4*)(te + (size_t)tok * 1024))[t];
    float4 p = ((const float4*)(pe + (size_t)s * 1024))[t];
    a.x += p.x; a.y += p.y; a.z += p.z; a.w += p.w;
    ((float4*)(h + (size_t)row * 1024))[t] = a;
}

// ---------------- LayerNorm: f32 in -> bf16 out, one block per row (D=1024) ----------------
__global__ void ln_k(const float* __restrict__ in, const float* __restrict__ g,
                     const float* __restrict__ b, u16* __restrict__ out) {
    int row = blockIdx.x;
    int t = threadIdx.x;
    float4 v = ((const float4*)(in + (size_t)row * 1024))[t];
    float s = v.x + v.y + v.z + v.w;
    float s2 = v.x * v.x + v.y * v.y + v.z * v.z + v.w * v.w;
    #pragma unroll
    for (int msk = 1; msk < 64; msk <<= 1) {
        s  += __shfl_xor(s, msk);
        s2 += __shfl_xor(s2, msk);
    }
    __shared__ float ps[4], ps2[4];
    if ((t & 63) == 0) { ps[t >> 6] = s; ps2[t >> 6] = s2; }
    __syncthreads();
    s = ps[0] + ps[1] + ps[2] + ps[3];
    s2 = ps2[0] + ps2[1] + ps2[2] + ps2[3];
    float mu = s * (1.0f / 1024.0f);
    float var = s2 * (1.0f / 1024.0f) - mu * mu;
    float rstd = rsqrtf(var + 1e-5f);
    float4 gg = ((const float4*)g)[t];
    float4 bb = ((const float4*)b)[t];
    ushort4 o;
    o.x = f2bf((v.x - mu) * rstd * gg.x + bb.x);
    o.y = f2bf((v.y - mu) * rstd * gg.y + bb.y);
    o.z = f2bf((v.z - mu) * rstd * gg.z + bb.z);
    o.w = f2bf((v.w - mu) * rstd * gg.w + bb.w);
    ((ushort4*)out)[(size_t)row * 256 + t] = o;
}

// ---------------- GEMM: C[m,n] = sum_k A[m,k] * Bw[n,k]  (both bf16 row-major) ----------------
// 128x128 tile, BK=32, 4 waves (2x2 of 64x64), 16x16x32 bf16 MFMA, global_load_lds staging.
template<int BIAS, int GELU_, int RES, int OUTBF>
__global__ void gemm_bt(const u16* __restrict__ A, const u16* __restrict__ Bw,
                        const float* __restrict__ bias, const float* __restrict__ res,
                        float* __restrict__ outf, u16* __restrict__ outb,
                        int M, int N, int K) {
    __shared__ u16 lA[128 * 32];
    __shared__ u16 lB[128 * 32];
    const int t = threadIdx.x;
    const int w = t >> 6, l = t & 63;
    const int m0 = blockIdx.x * 128;   // M fastest so concurrent blocks share B-panel
    const int n0 = blockIdx.y * 128;
    const int wr = (w >> 1) * 64, wc = (w & 1) * 64;
    const int fr = l & 15, fq = l >> 4;

    f32x4 acc[4][4] = {};
    const int g0 = w * 64 + l;

    for (int k0 = 0; k0 < K; k0 += 32) {
        #pragma unroll
        for (int i = 0; i < 2; ++i) {
            int g = g0 + i * 256;
            int row = g >> 2, c = (g & 3) * 8;
            const u16* ga = A  + (size_t)(m0 + row) * K + k0 + c;
            const u16* gb = Bw + (size_t)(n0 + row) * K + k0 + c;
            gload16(ga, lA + w * 512 + i * 2048);
            gload16(gb, lB + w * 512 + i * 2048);
        }
        __syncthreads();
        bf16x8 af[4], bfv[4];
        #pragma unroll
        for (int mi = 0; mi < 4; ++mi)
            af[mi] = *(const bf16x8*)(lA + (wr + mi * 16 + fr) * 32 + fq * 8);
        #pragma unroll
        for (int ni = 0; ni < 4; ++ni)
            bfv[ni] = *(const bf16x8*)(lB + (wc + ni * 16 + fr) * 32 + fq * 8);
        #pragma unroll
        for (int mi = 0; mi < 4; ++mi)
            #pragma unroll
            for (int ni = 0; ni < 4; ++ni)
                acc[mi][ni] = __builtin_amdgcn_mfma_f32_16x16x32_bf16(af[mi], bfv[ni], acc[mi][ni], 0, 0, 0);
        __syncthreads();
    }

    #pragma unroll
    for (int mi = 0; mi < 4; ++mi) {
        #pragma unroll
        for (int ni = 0; ni < 4; ++ni) {
            #pragma unroll
            for (int r = 0; r < 4; ++r) {
                int row = m0 + wr + mi * 16 + fq * 4 + r;
                int col = n0 + wc + ni * 16 + fr;
                float v = acc[mi][ni][r];
                if (BIAS) v += bias[col];
                if (GELU_) v = 0.5f * v * (1.0f + erff(v * 0.70710678118f));
                if (RES) v += res[(size_t)row * N + col];
                if (OUTBF) outb[(size_t)row * N + col] = f2bf(v);
                else       outf[(size_t)row * N + col] = v;
            }
        }
    }
}

// ---------------- Flash attention: one block per (qblock64, head, batch) ----------------
// qkv layout per row (3072): [q(16x64) | k(16x64) | v(16x64)], head-major inside each.
__global__ void attn_k(const u16* __restrict__ qkv, u16* __restrict__ o) {
    __shared__ u16 lK[64 * 64];       // [kv][d]
    __shared__ u16 lV[64 * 64];       // transposed: [d][kv]
    __shared__ u16 lP[4 * 16 * 64];   // per-wave P staging [wave][row16][kv64]
    const int t = threadIdx.x;
    const int w = t >> 6, l = t & 63;
    const int fr = l & 15, fq = l >> 4;
    const int b = blockIdx.z, hh = blockIdx.y, qb = blockIdx.x;
    const int q0 = qb * 64;

    bf16x8 qf[2];
    {
        size_t base = ((size_t)(b * 1024) + q0 + w * 16 + fr) * 3072 + hh * 64;
        qf[0] = *(const bf16x8*)(qkv + base + fq * 8);
        qf[1] = *(const bf16x8*)(qkv + base + 32 + fq * 8);
    }

    float m_run[4], l_run[4];
    f32x4 acc_o[4] = {};
    #pragma unroll
    for (int r = 0; r < 4; ++r) { m_run[r] = -__builtin_inff(); l_run[r] = 0.0f; }

    for (int kv0 = 0; kv0 <= q0; kv0 += 64) {
        // stage K tile via global_load_lds (linear [kv][d])
        #pragma unroll
        for (int i = 0; i < 2; ++i) {
            int g = w * 64 + l + i * 256;
            int row = g >> 3, c = (g & 7) * 8;
            const u16* gk = qkv + ((size_t)(b * 1024) + kv0 + row) * 3072 + 1024 + hh * 64 + c;
            gload16(gk, lK + w * 512 + i * 2048);
        }
        // stage V transposed (reg path)
        #pragma unroll
        for (int i = 0; i < 2; ++i) {
            int g = t + i * 256;
            int kv = g >> 3, d0 = (g & 7) * 8;
            const u32* gv = (const u32*)(qkv + ((size_t)(b * 1024) + kv0 + kv) * 3072 + 2048 + hh * 64 + d0);
            u32 v0 = gv[0], v1 = gv[1], v2 = gv[2], v3 = gv[3];
            u16 e[8] = { (u16)v0, (u16)(v0 >> 16), (u16)v1, (u16)(v1 >> 16),
                         (u16)v2, (u16)(v2 >> 16), (u16)v3, (u16)(v3 >> 16) };
            #pragma unroll
            for (int j = 0; j < 8; ++j) lV[(d0 + j) * 64 + kv] = e[j];
        }
        __syncthreads();

        // S = Q K^T (16 q-rows x 64 kv per wave)
        f32x4 accs[4] = {};
        #pragma unroll
        for (int nt = 0; nt < 4; ++nt) {
            #pragma unroll
            for (int ks = 0; ks < 2; ++ks) {
                bf16x8 kf = *(const bf16x8*)(lK + (nt * 16 + fr) * 64 + ks * 32 + fq * 8);
                accs[nt] = __builtin_amdgcn_mfma_f32_16x16x32_bf16(qf[ks], kf, accs[nt], 0, 0, 0);
            }
        }

        // online softmax
        float p[4][4], mx[4], rs[4];
        #pragma unroll
        for (int r = 0; r < 4; ++r) {
            int qg = q0 + w * 16 + fq * 4 + r;
            float m = -__builtin_inff();
            #pragma unroll
            for (int nt = 0; nt < 4; ++nt) {
                int kvg = kv0 + nt * 16 + fr;
                float s = (kvg <= qg) ? accs[nt][r] * 0.125f : -__builtin_inff();
                p[nt][r] = s;
                m = fmaxf(m, s);
            }
            mx[r] = m;
        }
        #pragma unroll
        for (int msk = 1; msk < 16; msk <<= 1) {
            #pragma unroll
            for (int r = 0; r < 4; ++r) mx[r] = fmaxf(mx[r], __shfl_xor(mx[r], msk));
        }
        float mnew[4], alpha[4];
        #pragma unroll
        for (int r = 0; r < 4; ++r) {
            mnew[r] = fmaxf(m_run[r], mx[r]);
            alpha[r] = __expf(m_run[r] - mnew[r]);
            float s = 0.0f;
            #pragma unroll
            for (int nt = 0; nt < 4; ++nt) {
                float pv = __expf(p[nt][r] - mnew[r]);
                p[nt][r] = pv;
                s += pv;
            }
            rs[r] = s;
        }
        #pragma unroll
        for (int msk = 1; msk < 16; msk <<= 1) {
            #pragma unroll
            for (int r = 0; r < 4; ++r) rs[r] += __shfl_xor(rs[r], msk);
        }
        #pragma unroll
        for (int r = 0; r < 4; ++r) {
            l_run[r] = l_run[r] * alpha[r] + rs[r];
            m_run[r] = mnew[r];
        }
        #pragma unroll
        for (int nt = 0; nt < 4; ++nt)
            #pragma unroll
            for (int r = 0; r < 4; ++r) acc_o[nt][r] *= alpha[r];

        // P -> LDS (bf16), then PV
        #pragma unroll
        for (int nt = 0; nt < 4; ++nt)
            #pragma unroll
            for (int r = 0; r < 4; ++r)
                lP[w * 1024 + (fq * 4 + r) * 64 + nt * 16 + fr] = f2bf(p[nt][r]);
        __syncthreads();

        bf16x8 pa[2];
        pa[0] = *(const bf16x8*)(lP + w * 1024 + fr * 64 + fq * 8);
        pa[1] = *(const bf16x8*)(lP + w * 1024 + fr * 64 + 32 + fq * 8);
        #pragma unroll
        for (int nt = 0; nt < 4; ++nt) {
            #pragma unroll
            for (int ks = 0; ks < 2; ++ks) {
                bf16x8 vf = *(const bf16x8*)(lV + (nt * 16 + fr) * 64 + ks * 32 + fq * 8);
                acc_o[nt] = __builtin_amdgcn_mfma_f32_16x16x32_bf16(pa[ks], vf, acc_o[nt], 0, 0, 0);
            }
        }
        __syncthreads();
    }

    // write O (B,S,D) with head offset
    #pragma unroll
    for (int nt = 0; nt < 4; ++nt) {
        #pragma unroll
        for (int r = 0; r < 4; ++r) {
            int qg = q0 + w * 16 + fq * 4 + r;
            int d = nt * 16 + fr;
            float ov = acc_o[nt][r] / l_run[r];
            o[((size_t)(b * 1024) + qg) * 1024 + hh * 64 + d] = f2bf(ov);
        }
    }
}

// ---------------- launch ----------------
extern "C" void kernel_launch(void* const* d_in, const int* in_sizes, int n_in,
                              void* d_out, int out_size, void* d_ws, size_t ws_size,
                              hipStream_t stream) {
    const int*   x       = (const int*)  d_in[0];
    const float* tok_emb = (const float*)d_in[1];
    const float* pos_emb = (const float*)d_in[2];
    const float* ln1_g   = (const float*)d_in[3];
    const float* ln1_b   = (const float*)d_in[4];
    const float* qkv_w   = (const float*)d_in[5];
    const float* qkv_b   = (const float*)d_in[6];
    const float* proj_w  = (const float*)d_in[7];
    const float* proj_b  = (const float*)d_in[8];
    const float* ln2_g   = (const float*)d_in[9];
    const float* ln2_b   = (const float*)d_in[10];
    const float* fc1_w   = (const float*)d_in[11];
    const float* fc1_b   = (const float*)d_in[12];
    const float* fc2_w   = (const float*)d_in[13];
    const float* fc2_b   = (const float*)d_in[14];
    const float* lnf_g   = (const float*)d_in[15];
    const float* lnf_b   = (const float*)d_in[16];
    const float* head_w  = (const float*)d_in[17];
    float* out = (float*)d_out;

    char* ws = (char*)d_ws;
    float* h   = (float*)(ws + 0);            //  8 MB f32 (2048x1024)
    u16*   xn  = (u16*)(ws + 8388608);        //  4 MB bf16
    u16*   qkv = (u16*)(ws + 12582912);       // 12.6 MB bf16 (2048x3072)
    u16*   ob  = (u16*)(ws + 25165824);       //  4 MB bf16
    u16*   ff  = (u16*)(ws + 29360128);       // 16.8 MB bf16 (2048x4096)
    u16*   wq  = (u16*)(ws + 46137344);       // 65.5 MB bf16 weight slab

    const int M = 2048;

    embed_k<<<dim3(2048), 256, 0, stream>>>(x, tok_emb, pos_emb, h);

    for (int lyr = 0; lyr < 6; ++lyr) {
        cvt_k<<<dim3(1024), 256, 0, stream>>>(qkv_w + (size_t)lyr * 3072 * 1024, wq, 3072 * 1024 / 4);
        ln_k<<<dim3(2048), 256, 0, stream>>>(h, ln1_g + lyr * 1024, ln1_b + lyr * 1024, xn);
        gemm_bt<1, 0, 0, 1><<<dim3(16, 24), 256, 0, stream>>>(
            xn, wq, qkv_b + lyr * 3072, nullptr, nullptr, qkv, M, 3072, 1024);
        attn_k<<<dim3(16, 16, 2), 256, 0, stream>>>(qkv, ob);
        cvt_k<<<dim3(1024), 256, 0, stream>>>(proj_w + (size_t)lyr * 1024 * 1024, wq, 1024 * 1024 / 4);
        gemm_bt<1, 0, 1, 0><<<dim3(16, 8), 256, 0, stream>>>(
            ob, wq, proj_b + lyr * 1024, h, h, nullptr, M, 1024, 1024);
        ln_k<<<dim3(2048), 256, 0, stream>>>(h, ln2_g + lyr * 1024, ln2_b + lyr * 1024, xn);
        cvt_k<<<dim3(1024), 256, 0, stream>>>(fc1_w + (size_t)lyr * 4096 * 1024, wq, 4096 * 1024 / 4);
        gemm_bt<1, 1, 0, 1><<<dim3(16, 32), 256, 0, stream>>>(
            xn, wq, fc1_b + lyr * 4096, nullptr, nullptr, ff, M, 4096, 1024);
        cvt_k<<<dim3(1024), 256, 0, stream>>>(fc2_w + (size_t)lyr * 1024 * 4096, wq, 1024 * 4096 / 4);
        gemm_bt<1, 0, 1, 0><<<dim3(16, 8), 256, 0, stream>>>(
            ff, wq, fc2_b + lyr * 1024, h, h, nullptr, M, 1024, 4096);
    }

    ln_k<<<dim3(2048), 256, 0, stream>>>(h, lnf_g, lnf_b, xn);
    cvt_k<<<dim3(2048), 256, 0, stream>>>(head_w, wq, 32000 * 1024 / 4);
    gemm_bt<0, 0, 0, 0><<<dim3(16, 250), 256, 0, stream>>>(
        xn, wq, nullptr, nullptr, out, nullptr, M, 32000, 1024);
}

// Round 2
// 1612.030 us; speedup vs baseline: 1.0684x; 1.0684x over previous
//
#include <hip/hip_runtime.h>

typedef unsigned short u16;
typedef unsigned int   u32;
typedef __bf16 bf16x8 __attribute__((ext_vector_type(8)));
typedef float  f32x4  __attribute__((ext_vector_type(4)));

#define DEV __device__ __forceinline__

DEV u16 f2bf(float f) {
    u32 u = __builtin_bit_cast(u32, f);
    u32 r = u + 0x7FFFu + ((u >> 16) & 1u);
    return (u16)(r >> 16);
}

DEV void gload16(const void* g, void* l) {
    __builtin_amdgcn_global_load_lds((const __attribute__((address_space(1))) void*)g,
                                     (__attribute__((address_space(3))) void*)l, 16, 0, 0);
}

// bijective XCD-aware swizzle (m204): contiguous tile chunk per XCD
DEV int xcd_swz(int bid, int nwg) {
    int q = nwg >> 3, r = nwg & 7;
    int xcd = bid & 7, idx = bid >> 3;
    return (xcd < r ? xcd * (q + 1) : r * (q + 1) + (xcd - r) * q) + idx;
}

// ---------------- convert f32 -> bf16 (vectorized, grid-stride) ----------------
__global__ void cvt_k(const float* __restrict__ src, u16* __restrict__ dst, int n4) {
    int i = blockIdx.x * blockDim.x + threadIdx.x;
    int stride = gridDim.x * blockDim.x;
    for (; i < n4; i += stride) {
        float4 v = ((const float4*)src)[i];
        ushort4 u;
        u.x = f2bf(v.x); u.y = f2bf(v.y); u.z = f2bf(v.z); u.w = f2bf(v.w);
        ((ushort4*)dst)[i] = u;
    }
}

// ---------------- embedding ----------------
__global__ void embed_k(const int* __restrict__ x, const float* __restrict__ te,
                        const float* __restrict__ pe, float* __restrict__ h) {
    int row = blockIdx.x;
    int t = threadIdx.x;
    int tok = x[row];
    int s = row & 1023;
    float4 a = ((const float4*)(te + (size_t)tok * 1024))[t];
    float4 p = ((const float4*)(pe + (size_t)s * 1024))[t];
    a.x += p.x; a.y += p.y; a.z += p.z; a.w += p.w;
    ((float4*)(h + (size_t)row * 1024))[t] = a;
}

// ---------------- LayerNorm: f32 in -> bf16 out ----------------
__global__ void ln_k(const float* __restrict__ in, const float* __restrict__ g,
                     const float* __restrict__ b, u16* __restrict__ out) {
    int row = blockIdx.x;
    int t = threadIdx.x;
    float4 v = ((const float4*)(in + (size_t)row * 1024))[t];
    float s = v.x + v.y + v.z + v.w;
    float s2 = v.x * v.x + v.y * v.y + v.z * v.z + v.w * v.w;
    #pragma unroll
    for (int msk = 1; msk < 64; msk <<= 1) {
        s  += __shfl_xor(s, msk);
        s2 += __shfl_xor(s2, msk);
    }
    __shared__ float ps[4], ps2[4];
    if ((t & 63) == 0) { ps[t >> 6] = s; ps2[t >> 6] = s2; }
    __syncthreads();
    s = ps[0] + ps[1] + ps[2] + ps[3];
    s2 = ps2[0] + ps2[1] + ps2[2] + ps2[3];
    float mu = s * (1.0f / 1024.0f);
    float var = s2 * (1.0f / 1024.0f) - mu * mu;
    float rstd = rsqrtf(var + 1e-5f);
    float4 gg = ((const float4*)g)[t];
    float4 bb = ((const float4*)b)[t];
    ushort4 o;
    o.x = f2bf((v.x - mu) * rstd * gg.x + bb.x);
    o.y = f2bf((v.y - mu) * rstd * gg.y + bb.y);
    o.z = f2bf((v.z - mu) * rstd * gg.z + bb.z);
    o.w = f2bf((v.w - mu) * rstd * gg.w + bb.w);
    ((ushort4*)out)[(size_t)row * 256 + t] = o;
}

// ---------------- GEMM: C[m,n] = sum_k A[m,k] * Bw[n,k] (bf16, B row-major N x K) ----------------
// BM x BN tile, BK=32, 4 waves (2x2), 16x16x32 bf16 MFMA, global_load_lds staging, XCD swizzle.
template<int BM, int BN, int BIAS, int GELU_, int RES, int OUTBF>
__global__ void gemm_bt(const u16* __restrict__ A, const u16* __restrict__ Bw,
                        const float* __restrict__ bias, const float* __restrict__ res,
                        float* __restrict__ outf, u16* __restrict__ outb,
                        int M, int N, int K) {
    constexpr int MR = BM / 32;      // M fragments per wave
    constexpr int NR = BN / 32;      // N fragments per wave
    constexpr int AL = BM / 64;      // A half-KB loads per thread
    constexpr int BL = BN / 64;
    __shared__ u16 lA[BM * 32];
    __shared__ u16 lB[BN * 32];
    const int t = threadIdx.x;
    const int w = t >> 6, l = t & 63;

    int bid = blockIdx.y * gridDim.x + blockIdx.x;     // x = m-index (fastest)
    int swz = xcd_swz(bid, gridDim.x * gridDim.y);
    const int m0 = (swz % gridDim.x) * BM;
    const int n0 = (swz / gridDim.x) * BN;

    const int wr = (w >> 1) * (BM / 2), wc = (w & 1) * (BN / 2);
    const int fr = l & 15, fq = l >> 4;

    f32x4 acc[MR][NR] = {};
    const int g0 = w * 64 + l;

    for (int k0 = 0; k0 < K; k0 += 32) {
        #pragma unroll
        for (int i = 0; i < AL; ++i) {
            int g = g0 + i * 256;
            int row = g >> 2, c = (g & 3) * 8;
            gload16(A + (size_t)(m0 + row) * K + k0 + c, lA + w * 512 + i * 2048);
        }
        #pragma unroll
        for (int i = 0; i < BL; ++i) {
            int g = g0 + i * 256;
            int row = g >> 2, c = (g & 3) * 8;
            gload16(Bw + (size_t)(n0 + row) * K + k0 + c, lB + w * 512 + i * 2048);
        }
        __syncthreads();
        bf16x8 af[MR], bfv[NR];
        #pragma unroll
        for (int mi = 0; mi < MR; ++mi)
            af[mi] = *(const bf16x8*)(lA + (wr + mi * 16 + fr) * 32 + fq * 8);
        #pragma unroll
        for (int ni = 0; ni < NR; ++ni)
            bfv[ni] = *(const bf16x8*)(lB + (wc + ni * 16 + fr) * 32 + fq * 8);
        #pragma unroll
        for (int mi = 0; mi < MR; ++mi)
            #pragma unroll
            for (int ni = 0; ni < NR; ++ni)
                acc[mi][ni] = __builtin_amdgcn_mfma_f32_16x16x32_bf16(af[mi], bfv[ni], acc[mi][ni], 0, 0, 0);
        __syncthreads();
    }

    #pragma unroll
    for (int mi = 0; mi < MR; ++mi) {
        #pragma unroll
        for (int ni = 0; ni < NR; ++ni) {
            #pragma unroll
            for (int r = 0; r < 4; ++r) {
                int row = m0 + wr + mi * 16 + fq * 4 + r;
                int col = n0 + wc + ni * 16 + fr;
                float v = acc[mi][ni][r];
                if (BIAS) v += bias[col];
                if (GELU_) v = 0.5f * v * (1.0f + erff(v * 0.70710678118f));
                if (RES) v += res[(size_t)row * N + col];
                if (OUTBF) outb[(size_t)row * N + col] = f2bf(v);
                else       outf[(size_t)row * N + col] = v;
            }
        }
    }
}

// ---------------- Flash attention: one block per (qblock64, head, batch) ----------------
__global__ void attn_k(const u16* __restrict__ qkv, u16* __restrict__ o) {
    __shared__ u16 lK[64 * 64];
    __shared__ u16 lV[64 * 64];       // transposed: [d][kv]
    __shared__ u16 lP[4 * 16 * 64];
    const int t = threadIdx.x;
    const int w = t >> 6, l = t & 63;
    const int fr = l & 15, fq = l >> 4;
    const int b = blockIdx.z, hh = blockIdx.y;
    const int qb = gridDim.x - 1 - blockIdx.x;   // long (high-qb) blocks dispatch first
    const int q0 = qb * 64;

    bf16x8 qf[2];
    {
        size_t base = ((size_t)(b * 1024) + q0 + w * 16 + fr) * 3072 + hh * 64;
        qf[0] = *(const bf16x8*)(qkv + base + fq * 8);
        qf[1] = *(const bf16x8*)(qkv + base + 32 + fq * 8);
    }

    float m_run[4], l_run[4];
    f32x4 acc_o[4] = {};
    #pragma unroll
    for (int r = 0; r < 4; ++r) { m_run[r] = -__builtin_inff(); l_run[r] = 0.0f; }

    for (int kv0 = 0; kv0 <= q0; kv0 += 64) {
        #pragma unroll
        for (int i = 0; i < 2; ++i) {
            int g = w * 64 + l + i * 256;
            int row = g >> 3, c = (g & 7) * 8;
            gload16(qkv + ((size_t)(b * 1024) + kv0 + row) * 3072 + 1024 + hh * 64 + c,
                    lK + w * 512 + i * 2048);
        }
        #pragma unroll
        for (int i = 0; i < 2; ++i) {
            int g = t + i * 256;
            int kv = g >> 3, d0 = (g & 7) * 8;
            const u32* gv = (const u32*)(qkv + ((size_t)(b * 1024) + kv0 + kv) * 3072 + 2048 + hh * 64 + d0);
            u32 v0 = gv[0], v1 = gv[1], v2 = gv[2], v3 = gv[3];
            u16 e[8] = { (u16)v0, (u16)(v0 >> 16), (u16)v1, (u16)(v1 >> 16),
                         (u16)v2, (u16)(v2 >> 16), (u16)v3, (u16)(v3 >> 16) };
            #pragma unroll
            for (int j = 0; j < 8; ++j) lV[(d0 + j) * 64 + kv] = e[j];
        }
        __syncthreads();

        f32x4 accs[4] = {};
        #pragma unroll
        for (int nt = 0; nt < 4; ++nt) {
            #pragma unroll
            for (int ks = 0; ks < 2; ++ks) {
                bf16x8 kf = *(const bf16x8*)(lK + (nt * 16 + fr) * 64 + ks * 32 + fq * 8);
                accs[nt] = __builtin_amdgcn_mfma_f32_16x16x32_bf16(qf[ks], kf, accs[nt], 0, 0, 0);
            }
        }

        float p[4][4], mx[4], rs[4];
        #pragma unroll
        for (int r = 0; r < 4; ++r) {
            int qg = q0 + w * 16 + fq * 4 + r;
            float m = -__builtin_inff();
            #pragma unroll
            for (int nt = 0; nt < 4; ++nt) {
                int kvg = kv0 + nt * 16 + fr;
                float s = (kvg <= qg) ? accs[nt][r] * 0.125f : -__builtin_inff();
                p[nt][r] = s;
                m = fmaxf(m, s);
            }
            mx[r] = m;
        }
        #pragma unroll
        for (int msk = 1; msk < 16; msk <<= 1) {
            #pragma unroll
            for (int r = 0; r < 4; ++r) mx[r] = fmaxf(mx[r], __shfl_xor(mx[r], msk));
        }
        float mnew[4], alpha[4];
        #pragma unroll
        for (int r = 0; r < 4; ++r) {
            mnew[r] = fmaxf(m_run[r], mx[r]);
            alpha[r] = __expf(m_run[r] - mnew[r]);
            float s = 0.0f;
            #pragma unroll
            for (int nt = 0; nt < 4; ++nt) {
                float pv = __expf(p[nt][r] - mnew[r]);
                p[nt][r] = pv;
                s += pv;
            }
            rs[r] = s;
        }
        #pragma unroll
        for (int msk = 1; msk < 16; msk <<= 1) {
            #pragma unroll
            for (int r = 0; r < 4; ++r) rs[r] += __shfl_xor(rs[r], msk);
        }
        #pragma unroll
        for (int r = 0; r < 4; ++r) {
            l_run[r] = l_run[r] * alpha[r] + rs[r];
            m_run[r] = mnew[r];
        }
        #pragma unroll
        for (int nt = 0; nt < 4; ++nt)
            #pragma unroll
            for (int r = 0; r < 4; ++r) acc_o[nt][r] *= alpha[r];

        #pragma unroll
        for (int nt = 0; nt < 4; ++nt)
            #pragma unroll
            for (int r = 0; r < 4; ++r)
                lP[w * 1024 + (fq * 4 + r) * 64 + nt * 16 + fr] = f2bf(p[nt][r]);
        __syncthreads();

        bf16x8 pa[2];
        pa[0] = *(const bf16x8*)(lP + w * 1024 + fr * 64 + fq * 8);
        pa[1] = *(const bf16x8*)(lP + w * 1024 + fr * 64 + 32 + fq * 8);
        #pragma unroll
        for (int nt = 0; nt < 4; ++nt) {
            #pragma unroll
            for (int ks = 0; ks < 2; ++ks) {
                bf16x8 vf = *(const bf16x8*)(lV + (nt * 16 + fr) * 64 + ks * 32 + fq * 8);
                acc_o[nt] = __builtin_amdgcn_mfma_f32_16x16x32_bf16(pa[ks], vf, acc_o[nt], 0, 0, 0);
            }
        }
        __syncthreads();
    }

    #pragma unroll
    for (int nt = 0; nt < 4; ++nt) {
        #pragma unroll
        for (int r = 0; r < 4; ++r) {
            int qg = q0 + w * 16 + fq * 4 + r;
            int d = nt * 16 + fr;
            float ov = acc_o[nt][r] / l_run[r];
            o[((size_t)(b * 1024) + qg) * 1024 + hh * 64 + d] = f2bf(ov);
        }
    }
}

// ---------------- launch ----------------
extern "C" void kernel_launch(void* const* d_in, const int* in_sizes, int n_in,
                              void* d_out, int out_size, void* d_ws, size_t ws_size,
                              hipStream_t stream) {
    const int*   x       = (const int*)  d_in[0];
    const float* tok_emb = (const float*)d_in[1];
    const float* pos_emb = (const float*)d_in[2];
    const float* ln1_g   = (const float*)d_in[3];
    const float* ln1_b   = (const float*)d_in[4];
    const float* qkv_w   = (const float*)d_in[5];
    const float* qkv_b   = (const float*)d_in[6];
    const float* proj_w  = (const float*)d_in[7];
    const float* proj_b  = (const float*)d_in[8];
    const float* ln2_g   = (const float*)d_in[9];
    const float* ln2_b   = (const float*)d_in[10];
    const float* fc1_w   = (const float*)d_in[11];
    const float* fc1_b   = (const float*)d_in[12];
    const float* fc2_w   = (const float*)d_in[13];
    const float* fc2_b   = (const float*)d_in[14];
    const float* lnf_g   = (const float*)d_in[15];
    const float* lnf_b   = (const float*)d_in[16];
    const float* head_w  = (const float*)d_in[17];
    float* out = (float*)d_out;

    char* ws = (char*)d_ws;
    float* h   = (float*)(ws + 0);            //  8 MB f32 (2048x1024)
    u16*   xn  = (u16*)(ws + 8388608);        //  4 MB bf16
    u16*   qkv = (u16*)(ws + 12582912);       // 12.6 MB bf16 (2048x3072)
    u16*   ob  = (u16*)(ws + 25165824);       //  4 MB bf16
    u16*   ff  = (u16*)(ws + 29360128);       // 16.8 MB bf16 (2048x4096)
    u16*   wq  = (u16*)(ws + 46137344);       // 65.5 MB bf16 weight slab

    const int M = 2048;

    embed_k<<<dim3(2048), 256, 0, stream>>>(x, tok_emb, pos_emb, h);

    for (int lyr = 0; lyr < 6; ++lyr) {
        cvt_k<<<dim3(1024), 256, 0, stream>>>(qkv_w + (size_t)lyr * 3072 * 1024, wq, 3072 * 1024 / 4);
        ln_k<<<dim3(2048), 256, 0, stream>>>(h, ln1_g + lyr * 1024, ln1_b + lyr * 1024, xn);
        gemm_bt<128, 128, 1, 0, 0, 1><<<dim3(16, 24), 256, 0, stream>>>(
            xn, wq, qkv_b + lyr * 3072, nullptr, nullptr, qkv, M, 3072, 1024);
        attn_k<<<dim3(16, 16, 2), 256, 0, stream>>>(qkv, ob);
        cvt_k<<<dim3(1024), 256, 0, stream>>>(proj_w + (size_t)lyr * 1024 * 1024, wq, 1024 * 1024 / 4);
        gemm_bt<128, 64, 1, 0, 1, 0><<<dim3(16, 16), 256, 0, stream>>>(
            ob, wq, proj_b + lyr * 1024, h, h, nullptr, M, 1024, 1024);
        ln_k<<<dim3(2048), 256, 0, stream>>>(h, ln2_g + lyr * 1024, ln2_b + lyr * 1024, xn);
        cvt_k<<<dim3(1024), 256, 0, stream>>>(fc1_w + (size_t)lyr * 4096 * 1024, wq, 4096 * 1024 / 4);
        gemm_bt<128, 128, 1, 1, 0, 1><<<dim3(16, 32), 256, 0, stream>>>(
            xn, wq, fc1_b + lyr * 4096, nullptr, nullptr, ff, M, 4096, 1024);
        cvt_k<<<dim3(1024), 256, 0, stream>>>(fc2_w + (size_t)lyr * 1024 * 4096, wq, 1024 * 4096 / 4);
        gemm_bt<128, 64, 1, 0, 1, 0><<<dim3(16, 16), 256, 0, stream>>>(
            ff, wq, fc2_b + lyr * 1024, h, h, nullptr, M, 1024, 4096);
    }

    ln_k<<<dim3(2048), 256, 0, stream>>>(h, lnf_g, lnf_b, xn);
    cvt_k<<<dim3(2048), 256, 0, stream>>>(head_w, wq, 32000 * 1024 / 4);
    gemm_bt<128, 128, 0, 0, 0, 0><<<dim3(16, 250), 256, 0, stream>>>(
        xn, wq, nullptr, nullptr, out, nullptr, M, 32000, 1024);
}